// Round 4
// baseline (631.553 us; speedup 1.0000x reference)
//
#include <hip/hip_runtime.h>

// ---- problem constants ----
#define KW 11
#define NB 2            // N * C
#define DI 96
#define HI 256
#define WI 256
#define DOUT 86
#define HOUT 246
#define WOUT 246
#define HT 16           // output tile height
#define WT 16           // output tile width
#define TH 16
#define TW 16
#define DCH 4           // chunks along D
#define DPC 22          // output d per chunk (22,22,22,20)
#define RR 26           // HT + KW - 1 region rows
#define RST 28          // dense row stride: 7 float4 per row (task idx == slot)
#define HSZ (HI * WI)
#define SSIM_C1 1e-4f
#define SSIM_C2 9e-4f
#define NBLK (TH * TW * NB * DCH)   // 2048
#define SLOT4 384       // float4 slots per slice buffer (364 real + 20 pad; %64==0)
#define SLICE_F (SLOT4 * 4)         // 1536 floats per slice

typedef const unsigned int __attribute__((address_space(1)))* gp1_t;
typedef unsigned int __attribute__((address_space(3)))* lp3_t;

__device__ __forceinline__ void gl_lds16(const float* g, float* l) {
    __builtin_amdgcn_global_load_lds((gp1_t)(const void*)g, (lp3_t)(void*)l, 16, 0, 0);
}

// Ring-buffer D-conv step with compile-time slot indices.
template<int J>
__device__ __forceinline__ void acc_step(
    float (&A)[KW], float (&B)[KW], float (&P)[KW], float (&Q)[KW],
    const float (&w)[KW], float f1, float f2, float f3, float f4,
    bool emit, float& o1, float& o2, float& o3, float& o4)
{
    #pragma unroll
    for (int p = 0; p < KW; ++p) {
        const int s = (J - p + KW) % KW;   // compile-time
        A[s] = fmaf(w[p], f1, A[s]);
        B[s] = fmaf(w[p], f2, B[s]);
        P[s] = fmaf(w[p], f3, P[s]);
        Q[s] = fmaf(w[p], f4, Q[s]);
    }
    const int C = (J + 1) % KW;            // completed slot
    if (emit) { o1 = A[C]; o2 = B[C]; o3 = P[C]; o4 = Q[C]; }
    A[C] = 0.f; B[C] = 0.f; P[C] = 0.f; Q[C] = 0.f;
}

static __global__ __launch_bounds__(256, 4) void ssim_main(
    const float* __restrict__ img1, const float* __restrict__ img2,
    const float* __restrict__ win, float* __restrict__ bsum)
{
    __shared__ __align__(16) float rawf[2 * SLICE_F];    // 12288 B, 2 slices
    __shared__ __align__(16) float4 A4[2][RR][WT + 1];   // 14144 B
    __shared__ float w1s[KW];
    __shared__ float tmpw[121];
    __shared__ float red[4];

    const int t = threadIdx.x;
    const int bz = blockIdx.z;            // n*4 + chunk
    const int n = bz >> 2, chunk = bz & 3;
    const int d0 = chunk * DPC;
    const int dpc = (DOUT - d0 < DPC) ? (DOUT - d0) : DPC;
    const int NIT = (dpc + KW - 1) >> 1;   // 16 or 15 iterations, 2 slices each
    const int h0 = blockIdx.y * HT, w0 = blockIdx.x * WT;

    // 1-D separable profile from marginal sums of the 3-D window.
    if (t < 121) {
        const int i = t / KW, j = t - i * KW;
        const float* wp = win + i * (KW * KW) + j * KW;
        float s = 0.f;
        #pragma unroll
        for (int m = 0; m < KW; ++m) s += wp[m];
        tmpw[t] = s;
    }
    __syncthreads();
    if (t < KW) {
        float s = 0.f;
        #pragma unroll
        for (int j = 0; j < KW; ++j) s += tmpw[t * KW + j];
        w1s[t] = s;
    }
    __syncthreads();
    float w1r[KW];
    #pragma unroll
    for (int k = 0; k < KW; ++k) w1r[k] = w1s[k];

    // ---- staging task setup: 3 tasks/thread, u = t + 256q, u in [0,768) ----
    // LDS float4 slot == u (dense layout); per-lane global src, wave-linear dest.
    const float* tp[3];
    int tstr[3];
    float* tl[3];
    #pragma unroll
    for (int q = 0; q < 3; ++q) {
        const int u = t + 256 * q;
        const int sl = (u >= SLOT4) ? 1 : 0;
        const int v = u - sl * SLOT4;
        const int img = (v >= 182) ? 1 : 0;
        const int vv = v - 182 * img;
        const int r = vv / 7, c4 = vv - 7 * r;
        const int gh = h0 + r, gw0 = w0 + 4 * c4;
        const bool oob = (v >= 364) || (gh >= HI) || (gw0 >= WI);
        const float* base = img ? img2 : img1;
        tp[q] = oob ? img1
                    : base + ((long)(n * DI + d0 + sl) * HSZ + (long)gh * WI + gw0);
        tstr[q] = oob ? 0 : 2 * HSZ;      // advance 2 slices per iteration
        tl[q] = &rawf[4 * u];
    }

    // D-conv ring accumulators: 4 fields (a, b, ab, a^2+b^2).
    float rA[KW], rB[KW], rP[KW], rQ[KW];
    #pragma unroll
    for (int p = 0; p < KW; ++p) { rA[p]=0.f; rB[p]=0.f; rP[p]=0.f; rQ[p]=0.f; }

    const int ty = t >> 4, tx = t & 15;
    const bool valid = (h0 + ty < HOUT) && (w0 + tx < WOUT);
    float partial = 0.f;

    // Phase A worker: one 2-output W-conv task; u in [0,416).
    auto phaseA = [&](int u) {
        const int sl = (u >= 208) ? 1 : 0;
        const int v = u - sl * 208;
        const int r = v >> 3, c0 = (v & 7) * 2;
        const float* r0 = &rawf[sl * SLICE_F + r * RST + c0];
        const float* r1 = r0 + 182 * 4;    // img2 plane offset (728 floats)
        float xa[12], xb[12];
        #pragma unroll
        for (int m = 0; m < 6; ++m) {
            const float2 va = *(const float2*)(r0 + 2 * m);
            const float2 vb = *(const float2*)(r1 + 2 * m);
            xa[2*m] = va.x; xa[2*m+1] = va.y;
            xb[2*m] = vb.x; xb[2*m+1] = vb.y;
        }
        float s1[2] = {0.f,0.f}, s2[2] = {0.f,0.f};
        #pragma unroll
        for (int k = 0; k < KW; ++k) {
            const float wk = w1r[k];
            s1[0] = fmaf(wk, xa[k],   s1[0]);
            s1[1] = fmaf(wk, xa[k+1], s1[1]);
            s2[0] = fmaf(wk, xb[k],   s2[0]);
            s2[1] = fmaf(wk, xb[k+1], s2[1]);
        }
        #pragma unroll
        for (int m = 0; m < 12; ++m) {     // hoist products: xa<-x*y, xb<-x^2+y^2
            const float x = xa[m], y = xb[m];
            xa[m] = x * y;
            xb[m] = fmaf(x, x, y * y);
        }
        float s3[2] = {0.f,0.f}, s4[2] = {0.f,0.f};
        #pragma unroll
        for (int k = 0; k < KW; ++k) {
            const float wk = w1r[k];
            s3[0] = fmaf(wk, xa[k],   s3[0]);
            s3[1] = fmaf(wk, xa[k+1], s3[1]);
            s4[0] = fmaf(wk, xb[k],   s4[0]);
            s4[1] = fmaf(wk, xb[k+1], s4[1]);
        }
        A4[sl][r][c0]     = make_float4(s1[0], s2[0], s3[0], s4[0]);
        A4[sl][r][c0 + 1] = make_float4(s1[1], s2[1], s3[1], s4[1]);
    };

    // ---- prologue: stage slices d0, d0+1 directly to LDS ----
    gl_lds16(tp[0], tl[0]); gl_lds16(tp[1], tl[1]); gl_lds16(tp[2], tl[2]);
    tp[0] += tstr[0]; tp[1] += tstr[1]; tp[2] += tstr[2];
    __syncthreads();   // drains vmcnt -> raw ready

    int jj = 0;        // (2i) % 11
    for (int i = 0; i < NIT; ++i) {
        // ---- phase A: both slices' W-convs (416 tasks over 256 threads) ----
        phaseA(t);
        if (t < 160) phaseA(t + 256);
        __syncthreads();   // A4 ready; raw fully consumed

        // ---- issue staging for next slice pair (lands before next barrier) ----
        if (i + 1 < NIT) {
            gl_lds16(tp[0], tl[0]); gl_lds16(tp[1], tl[1]); gl_lds16(tp[2], tl[2]);
            tp[0] += tstr[0]; tp[1] += tstr[1]; tp[2] += tstr[2];
        }

        // ---- phase B: H-conv both slices, ring x2, emit x2 ----
        float fa1=0.f, fa2=0.f, fa3=0.f, fa4=0.f;
        float fb1=0.f, fb2=0.f, fb3=0.f, fb4=0.f;
        #pragma unroll
        for (int kh = 0; kh < KW; ++kh) {
            const float w = w1r[kh];
            const float4 va = A4[0][ty + kh][tx];
            const float4 vb = A4[1][ty + kh][tx];
            fa1 = fmaf(w, va.x, fa1); fa2 = fmaf(w, va.y, fa2);
            fa3 = fmaf(w, va.z, fa3); fa4 = fmaf(w, va.w, fa4);
            fb1 = fmaf(w, vb.x, fb1); fb2 = fmaf(w, vb.y, fb2);
            fb3 = fmaf(w, vb.z, fb3); fb4 = fmaf(w, vb.w, fb4);
        }

        const bool emit = (i >= 5);
        float oa1=0.f, oa2=0.f, oa3=0.f, oa4=0.f;
        float ob1=0.f, ob2=0.f, ob3=0.f, ob4=0.f;
        switch (jj) {
            #define CASE2(J) case J: \
                acc_step<J>(rA,rB,rP,rQ,w1r,fa1,fa2,fa3,fa4,emit,oa1,oa2,oa3,oa4); \
                acc_step<(J+1)%KW>(rA,rB,rP,rQ,w1r,fb1,fb2,fb3,fb4,emit,ob1,ob2,ob3,ob4); \
                break;
            CASE2(0) CASE2(1) CASE2(2) CASE2(3) CASE2(4) CASE2(5)
            CASE2(6) CASE2(7) CASE2(8) CASE2(9) CASE2(10)
            #undef CASE2
        }
        jj += 2; if (jj >= KW) jj -= KW;

        if (emit && valid) {
            {
                const float m11 = oa1 * oa1, m22 = oa2 * oa2, m12 = oa1 * oa2;
                const float num = (2.f * m12 + SSIM_C1) * (2.f * (oa3 - m12) + SSIM_C2);
                const float den = (m11 + m22 + SSIM_C1) * ((oa4 - m11 - m22) + SSIM_C2);
                partial += num * __builtin_amdgcn_rcpf(den);
            }
            {
                const float m11 = ob1 * ob1, m22 = ob2 * ob2, m12 = ob1 * ob2;
                const float num = (2.f * m12 + SSIM_C1) * (2.f * (ob3 - m12) + SSIM_C2);
                const float den = (m11 + m22 + SSIM_C1) * ((ob4 - m11 - m22) + SSIM_C2);
                partial += num * __builtin_amdgcn_rcpf(den);
            }
        }
        __syncthreads();   // new raw staged + A4 consumed -> next iteration
    }

    // ---- block reduction -> per-block partial sum ----
    #pragma unroll
    for (int off = 32; off >= 1; off >>= 1)
        partial += __shfl_down(partial, off, 64);
    if ((t & 63) == 0) red[t >> 6] = partial;
    __syncthreads();
    if (t == 0) {
        bsum[(blockIdx.z * gridDim.y + blockIdx.y) * gridDim.x + blockIdx.x]
            = red[0] + red[1] + red[2] + red[3];
    }
}

static __global__ __launch_bounds__(256) void ssim_reduce(
    const float* __restrict__ bsum, float* __restrict__ out)
{
    __shared__ double red[4];
    const int t = threadIdx.x;
    double s = 0.0;
    for (int i = t; i < NBLK; i += 256) s += (double)bsum[i];
    #pragma unroll
    for (int off = 32; off >= 1; off >>= 1)
        s += __shfl_down(s, off, 64);
    if ((t & 63) == 0) red[t >> 6] = s;
    __syncthreads();
    if (t == 0) {
        const double tot = red[0] + red[1] + red[2] + red[3];
        out[0] = (float)(tot / (double)((long)NB * DOUT * HOUT * WOUT));
    }
}

extern "C" void kernel_launch(void* const* d_in, const int* in_sizes, int n_in,
                              void* d_out, int out_size, void* d_ws, size_t ws_size,
                              hipStream_t stream)
{
    const float* img1 = (const float*)d_in[0];
    const float* img2 = (const float*)d_in[1];
    const float* win  = (const float*)d_in[2];
    float* out  = (float*)d_out;
    float* bsum = (float*)d_ws;   // 2048 floats = 8 KB scratch

    dim3 grid(TW, TH, NB * DCH);
    ssim_main<<<grid, 256, 0, stream>>>(img1, img2, win, bsum);
    ssim_reduce<<<1, 256, 0, stream>>>(bsum, out);
}

// Round 5
// 164.036 us; speedup vs baseline: 3.8501x; 3.8501x over previous
//
#include <hip/hip_runtime.h>

// ---- problem constants ----
#define KW 11
#define NB 2            // N * C
#define DI 96
#define HI 256
#define WI 256
#define DOUT 86
#define HOUT 246
#define WOUT 246
#define HT 16           // output tile height
#define WT 16           // output tile width
#define TH 16
#define TW 16
#define DCH 4           // chunks along D
#define DPC 22          // output d per chunk (22,22,22,20)
#define RR 26           // HT + KW - 1 region rows
#define RST 28          // dense row stride: 7 float4 per row (task idx == slot)
#define HSZ (HI * WI)
#define SSIM_C1 1e-4f
#define SSIM_C2 9e-4f
#define NBLK (TH * TW * NB * DCH)   // 2048
#define SLOT4 384       // float4 slots per slice buffer (364 real + 20 pad; %64==0)
#define SLICE_F (SLOT4 * 4)         // 1536 floats per slice

typedef const unsigned int __attribute__((address_space(1)))* gp1_t;
typedef unsigned int __attribute__((address_space(3)))* lp3_t;

__device__ __forceinline__ void gl_lds16(const float* g, float* l) {
    __builtin_amdgcn_global_load_lds((gp1_t)(const void*)g, (lp3_t)(void*)l, 16, 0, 0);
}

// Ring-buffer D-conv step with compile-time slot indices.
template<int J>
__device__ __forceinline__ void acc_step(
    float (&A)[KW], float (&B)[KW], float (&P)[KW], float (&Q)[KW],
    const float (&w)[KW], float f1, float f2, float f3, float f4,
    bool emit, float& o1, float& o2, float& o3, float& o4)
{
    #pragma unroll
    for (int p = 0; p < KW; ++p) {
        const int s = (J - p + KW) % KW;   // compile-time
        A[s] = fmaf(w[p], f1, A[s]);
        B[s] = fmaf(w[p], f2, B[s]);
        P[s] = fmaf(w[p], f3, P[s]);
        Q[s] = fmaf(w[p], f4, Q[s]);
    }
    const int C = (J + 1) % KW;            // completed slot
    if (emit) { o1 = A[C]; o2 = B[C]; o3 = P[C]; o4 = Q[C]; }
    A[C] = 0.f; B[C] = 0.f; P[C] = 0.f; Q[C] = 0.f;
}

// NOTE: min-waves/EU = 2 (VGPR cap 256). (256,4) caps VGPRs at 64 and spills
// ~45 regs/thread to scratch -> 1.1 GB of HBM write traffic, 3x slowdown (R4).
static __global__ __launch_bounds__(256, 2) void ssim_main(
    const float* __restrict__ img1, const float* __restrict__ img2,
    const float* __restrict__ win, float* __restrict__ bsum)
{
    __shared__ __align__(16) float rawf[2 * SLICE_F];    // 12288 B, 2 slices
    __shared__ __align__(16) float4 A4[2][RR][WT + 1];   // 14144 B
    __shared__ float w1s[KW];
    __shared__ float tmpw[121];
    __shared__ float red[4];

    const int t = threadIdx.x;
    const int bz = blockIdx.z;            // n*4 + chunk
    const int n = bz >> 2, chunk = bz & 3;
    const int d0 = chunk * DPC;
    const int dpc = (DOUT - d0 < DPC) ? (DOUT - d0) : DPC;
    const int NIT = (dpc + KW - 1) >> 1;   // 16 or 15 iterations, 2 slices each
    const int h0 = blockIdx.y * HT, w0 = blockIdx.x * WT;

    // 1-D separable profile from marginal sums of the 3-D window.
    if (t < 121) {
        const int i = t / KW, j = t - i * KW;
        const float* wp = win + i * (KW * KW) + j * KW;
        float s = 0.f;
        #pragma unroll
        for (int m = 0; m < KW; ++m) s += wp[m];
        tmpw[t] = s;
    }
    __syncthreads();
    if (t < KW) {
        float s = 0.f;
        #pragma unroll
        for (int j = 0; j < KW; ++j) s += tmpw[t * KW + j];
        w1s[t] = s;
    }
    __syncthreads();
    float w1r[KW];
    #pragma unroll
    for (int k = 0; k < KW; ++k) w1r[k] = w1s[k];

    // ---- staging task setup: 3 tasks/thread, u = t + 256q, u in [0,768) ----
    // LDS float4 slot == u (dense layout); per-lane global src, wave-linear dest.
    const float* tp[3];
    int tstr[3];
    float* tl[3];
    #pragma unroll
    for (int q = 0; q < 3; ++q) {
        const int u = t + 256 * q;
        const int sl = (u >= SLOT4) ? 1 : 0;
        const int v = u - sl * SLOT4;
        const int img = (v >= 182) ? 1 : 0;
        const int vv = v - 182 * img;
        const int r = vv / 7, c4 = vv - 7 * r;
        const int gh = h0 + r, gw0 = w0 + 4 * c4;
        const bool oob = (v >= 364) || (gh >= HI) || (gw0 >= WI);
        const float* base = img ? img2 : img1;
        tp[q] = oob ? img1
                    : base + ((long)(n * DI + d0 + sl) * HSZ + (long)gh * WI + gw0);
        tstr[q] = oob ? 0 : 2 * HSZ;      // advance 2 slices per iteration
        tl[q] = &rawf[4 * u];
    }

    // D-conv ring accumulators: 4 fields (a, b, ab, a^2+b^2).
    float rA[KW], rB[KW], rP[KW], rQ[KW];
    #pragma unroll
    for (int p = 0; p < KW; ++p) { rA[p]=0.f; rB[p]=0.f; rP[p]=0.f; rQ[p]=0.f; }

    const int ty = t >> 4, tx = t & 15;
    const bool valid = (h0 + ty < HOUT) && (w0 + tx < WOUT);
    float partial = 0.f;

    // Phase A worker: one 2-output W-conv task; u in [0,416).
    auto phaseA = [&](int u) {
        const int sl = (u >= 208) ? 1 : 0;
        const int v = u - sl * 208;
        const int r = v >> 3, c0 = (v & 7) * 2;
        const float* r0 = &rawf[sl * SLICE_F + r * RST + c0];
        const float* r1 = r0 + 182 * 4;    // img2 plane offset (728 floats)
        float xa[12], xb[12];
        #pragma unroll
        for (int m = 0; m < 6; ++m) {
            const float2 va = *(const float2*)(r0 + 2 * m);
            const float2 vb = *(const float2*)(r1 + 2 * m);
            xa[2*m] = va.x; xa[2*m+1] = va.y;
            xb[2*m] = vb.x; xb[2*m+1] = vb.y;
        }
        float s1[2] = {0.f,0.f}, s2[2] = {0.f,0.f};
        #pragma unroll
        for (int k = 0; k < KW; ++k) {
            const float wk = w1r[k];
            s1[0] = fmaf(wk, xa[k],   s1[0]);
            s1[1] = fmaf(wk, xa[k+1], s1[1]);
            s2[0] = fmaf(wk, xb[k],   s2[0]);
            s2[1] = fmaf(wk, xb[k+1], s2[1]);
        }
        #pragma unroll
        for (int m = 0; m < 12; ++m) {     // hoist products: xa<-x*y, xb<-x^2+y^2
            const float x = xa[m], y = xb[m];
            xa[m] = x * y;
            xb[m] = fmaf(x, x, y * y);
        }
        float s3[2] = {0.f,0.f}, s4[2] = {0.f,0.f};
        #pragma unroll
        for (int k = 0; k < KW; ++k) {
            const float wk = w1r[k];
            s3[0] = fmaf(wk, xa[k],   s3[0]);
            s3[1] = fmaf(wk, xa[k+1], s3[1]);
            s4[0] = fmaf(wk, xb[k],   s4[0]);
            s4[1] = fmaf(wk, xb[k+1], s4[1]);
        }
        A4[sl][r][c0]     = make_float4(s1[0], s2[0], s3[0], s4[0]);
        A4[sl][r][c0 + 1] = make_float4(s1[1], s2[1], s3[1], s4[1]);
    };

    // ---- prologue: stage slices d0, d0+1 directly to LDS ----
    gl_lds16(tp[0], tl[0]); gl_lds16(tp[1], tl[1]); gl_lds16(tp[2], tl[2]);
    tp[0] += tstr[0]; tp[1] += tstr[1]; tp[2] += tstr[2];
    __syncthreads();   // drains vmcnt -> raw ready

    int jj = 0;        // (2i) % 11
    for (int i = 0; i < NIT; ++i) {
        // ---- phase A: both slices' W-convs (416 tasks over 256 threads) ----
        phaseA(t);
        if (t < 160) phaseA(t + 256);
        __syncthreads();   // A4 ready; raw fully consumed

        // ---- issue staging for next slice pair (lands before next barrier) ----
        if (i + 1 < NIT) {
            gl_lds16(tp[0], tl[0]); gl_lds16(tp[1], tl[1]); gl_lds16(tp[2], tl[2]);
            tp[0] += tstr[0]; tp[1] += tstr[1]; tp[2] += tstr[2];
        }

        // ---- phase B: H-conv both slices, ring x2, emit x2 ----
        float fa1=0.f, fa2=0.f, fa3=0.f, fa4=0.f;
        float fb1=0.f, fb2=0.f, fb3=0.f, fb4=0.f;
        #pragma unroll
        for (int kh = 0; kh < KW; ++kh) {
            const float w = w1r[kh];
            const float4 va = A4[0][ty + kh][tx];
            const float4 vb = A4[1][ty + kh][tx];
            fa1 = fmaf(w, va.x, fa1); fa2 = fmaf(w, va.y, fa2);
            fa3 = fmaf(w, va.z, fa3); fa4 = fmaf(w, va.w, fa4);
            fb1 = fmaf(w, vb.x, fb1); fb2 = fmaf(w, vb.y, fb2);
            fb3 = fmaf(w, vb.z, fb3); fb4 = fmaf(w, vb.w, fb4);
        }

        const bool emit = (i >= 5);
        float oa1=0.f, oa2=0.f, oa3=0.f, oa4=0.f;
        float ob1=0.f, ob2=0.f, ob3=0.f, ob4=0.f;
        switch (jj) {
            #define CASE2(J) case J: \
                acc_step<J>(rA,rB,rP,rQ,w1r,fa1,fa2,fa3,fa4,emit,oa1,oa2,oa3,oa4); \
                acc_step<(J+1)%KW>(rA,rB,rP,rQ,w1r,fb1,fb2,fb3,fb4,emit,ob1,ob2,ob3,ob4); \
                break;
            CASE2(0) CASE2(1) CASE2(2) CASE2(3) CASE2(4) CASE2(5)
            CASE2(6) CASE2(7) CASE2(8) CASE2(9) CASE2(10)
            #undef CASE2
        }
        jj += 2; if (jj >= KW) jj -= KW;

        if (emit && valid) {
            {
                const float m11 = oa1 * oa1, m22 = oa2 * oa2, m12 = oa1 * oa2;
                const float num = (2.f * m12 + SSIM_C1) * (2.f * (oa3 - m12) + SSIM_C2);
                const float den = (m11 + m22 + SSIM_C1) * ((oa4 - m11 - m22) + SSIM_C2);
                partial += num * __builtin_amdgcn_rcpf(den);
            }
            {
                const float m11 = ob1 * ob1, m22 = ob2 * ob2, m12 = ob1 * ob2;
                const float num = (2.f * m12 + SSIM_C1) * (2.f * (ob3 - m12) + SSIM_C2);
                const float den = (m11 + m22 + SSIM_C1) * ((ob4 - m11 - m22) + SSIM_C2);
                partial += num * __builtin_amdgcn_rcpf(den);
            }
        }
        __syncthreads();   // new raw staged + A4 consumed -> next iteration
    }

    // ---- block reduction -> per-block partial sum ----
    #pragma unroll
    for (int off = 32; off >= 1; off >>= 1)
        partial += __shfl_down(partial, off, 64);
    if ((t & 63) == 0) red[t >> 6] = partial;
    __syncthreads();
    if (t == 0) {
        bsum[(blockIdx.z * gridDim.y + blockIdx.y) * gridDim.x + blockIdx.x]
            = red[0] + red[1] + red[2] + red[3];
    }
}

static __global__ __launch_bounds__(256) void ssim_reduce(
    const float* __restrict__ bsum, float* __restrict__ out)
{
    __shared__ double red[4];
    const int t = threadIdx.x;
    double s = 0.0;
    for (int i = t; i < NBLK; i += 256) s += (double)bsum[i];
    #pragma unroll
    for (int off = 32; off >= 1; off >>= 1)
        s += __shfl_down(s, off, 64);
    if ((t & 63) == 0) red[t >> 6] = s;
    __syncthreads();
    if (t == 0) {
        const double tot = red[0] + red[1] + red[2] + red[3];
        out[0] = (float)(tot / (double)((long)NB * DOUT * HOUT * WOUT));
    }
}

extern "C" void kernel_launch(void* const* d_in, const int* in_sizes, int n_in,
                              void* d_out, int out_size, void* d_ws, size_t ws_size,
                              hipStream_t stream)
{
    const float* img1 = (const float*)d_in[0];
    const float* img2 = (const float*)d_in[1];
    const float* win  = (const float*)d_in[2];
    float* out  = (float*)d_out;
    float* bsum = (float*)d_ws;   // 2048 floats = 8 KB scratch

    dim3 grid(TW, TH, NB * DCH);
    ssim_main<<<grid, 256, 0, stream>>>(img1, img2, win, bsum);
    ssim_reduce<<<1, 256, 0, stream>>>(bsum, out);
}

// Round 6
// 157.793 us; speedup vs baseline: 4.0024x; 1.0396x over previous
//
#include <hip/hip_runtime.h>

// ---- problem constants ----
#define KW 11
#define NB 2            // N * C
#define DI 96
#define HI 256
#define WI 256
#define DOUT 86
#define HOUT 246
#define WOUT 246
#define HT 16           // output tile height
#define WT 16           // output tile width
#define TH 16
#define TW 16
#define DCH 4           // chunks along D
#define DPC 22          // output d per chunk (22,22,22,20)
#define RR 26           // HT + KW - 1 region rows
#define HSZ (HI * WI)
#define SSIM_C1 1e-4f
#define SSIM_C2 9e-4f
#define NBLK (TH * TW * NB * DCH)   // 2048
// raw slice layout: 26 rows x [img1: 28 floats | img2: 28 floats] = 1456 floats
// = 364 float4 slots, padded to 384 (%64==0 for wave-linear global_load_lds).
#define SLOT4 384
#define SLICE_F (SLOT4 * 4)         // 1536 floats per slice
#define ROWF 56                     // floats per interleaved row

typedef const unsigned int __attribute__((address_space(1)))* gp1_t;
typedef unsigned int __attribute__((address_space(3)))* lp3_t;
using f32x2 = __attribute__((ext_vector_type(2))) float;

__device__ __forceinline__ void gl_lds16(const float* g, float* l) {
    __builtin_amdgcn_global_load_lds((gp1_t)(const void*)g, (lp3_t)(void*)l, 16, 0, 0);
}

// packed fp32 FMA: d = w*x + acc per 32-bit half; w is wave-uniform (SGPR pair).
__device__ __forceinline__ f32x2 pk_fma_s(f32x2 w, f32x2 x, f32x2 acc) {
    f32x2 d;
    asm("v_pk_fma_f32 %0, %1, %2, %3" : "=v"(d) : "s"(w), "v"(x), "v"(acc));
    return d;
}

__device__ __forceinline__ float rfl(float x) {
    return __int_as_float(__builtin_amdgcn_readfirstlane(__float_as_int(x)));
}

// Packed ring-buffer D-conv step with compile-time slot indices.
// AB = (mu1, mu2) fields; PQ = (E[xy], E[x^2+y^2]) fields.
template<int J>
__device__ __forceinline__ void acc_step(
    f32x2 (&AB)[KW], f32x2 (&PQ)[KW], const f32x2 (&w2)[KW],
    f32x2 f12, f32x2 f34, bool emit, f32x2& o12, f32x2& o34)
{
    #pragma unroll
    for (int p = 0; p < KW; ++p) {
        const int s = (J - p + KW) % KW;   // compile-time
        AB[s] = pk_fma_s(w2[p], f12, AB[s]);
        PQ[s] = pk_fma_s(w2[p], f34, PQ[s]);
    }
    const int C = (J + 1) % KW;            // completed slot
    if (emit) { o12 = AB[C]; o34 = PQ[C]; }
    AB[C] = (f32x2){0.f, 0.f};
    PQ[C] = (f32x2){0.f, 0.f};
}

// NOTE: min-waves/EU = 2 (VGPR cap 256). (256,4) caps VGPRs at 64 and spills
// ~45 regs/thread -> 1.1 GB HBM write traffic, 3x slowdown (R4).
static __global__ __launch_bounds__(256, 2) void ssim_main(
    const float* __restrict__ img1, const float* __restrict__ img2,
    const float* __restrict__ win, float* __restrict__ bsum)
{
    __shared__ __align__(16) float rawf[2 * SLICE_F];    // 12288 B, 2 slices
    __shared__ __align__(16) float4 A4[2][RR][WT + 1];   // 14144 B
    __shared__ float w1s[KW];
    __shared__ float tmpw[121];
    __shared__ float red[4];

    const int t = threadIdx.x;
    const int bz = blockIdx.z;            // n*4 + chunk
    const int n = bz >> 2, chunk = bz & 3;
    const int d0 = chunk * DPC;
    const int dpc = (DOUT - d0 < DPC) ? (DOUT - d0) : DPC;
    const int NIT = (dpc + KW - 1) >> 1;   // 16 or 15 iterations, 2 slices each
    const int h0 = blockIdx.y * HT, w0 = blockIdx.x * WT;

    // 1-D separable profile from marginal sums of the 3-D window.
    if (t < 121) {
        const int i = t / KW, j = t - i * KW;
        const float* wp = win + i * (KW * KW) + j * KW;
        float s = 0.f;
        #pragma unroll
        for (int m = 0; m < KW; ++m) s += wp[m];
        tmpw[t] = s;
    }
    __syncthreads();
    if (t < KW) {
        float s = 0.f;
        #pragma unroll
        for (int j = 0; j < KW; ++j) s += tmpw[t * KW + j];
        w1s[t] = s;
    }
    __syncthreads();
    f32x2 w2[KW];                          // wave-uniform -> SGPR pairs
    #pragma unroll
    for (int k = 0; k < KW; ++k) {
        const float ws = rfl(w1s[k]);
        w2[k] = (f32x2){ws, ws};
    }

    // ---- staging task setup: 3 tasks/thread, u = t + 256q, u in [0,768) ----
    // slot u -> slice sl, row r = v/14, half (img), c4 = col-group.
    const float* tp[3];
    int tstr[3];
    float* tl[3];
    #pragma unroll
    for (int q = 0; q < 3; ++q) {
        const int u = t + 256 * q;
        const int sl = (u >= SLOT4) ? 1 : 0;
        const int v = u - sl * SLOT4;
        const int r = v / 14;
        const int rem = v - 14 * r;
        const int img = (rem >= 7) ? 1 : 0;
        const int c4 = rem - 7 * img;
        const int gh = h0 + r, gw0 = w0 + 4 * c4;
        const bool oob = (v >= 364) || (gh >= HI) || (gw0 >= WI);
        const float* base = img ? img2 : img1;
        tp[q] = oob ? img1
                    : base + ((long)(n * DI + d0 + sl) * HSZ + (long)gh * WI + gw0);
        tstr[q] = oob ? 0 : 2 * HSZ;      // advance 2 slices per iteration
        tl[q] = &rawf[4 * u];
    }

    // Packed D-conv ring accumulators.
    f32x2 rAB[KW], rPQ[KW];
    #pragma unroll
    for (int p = 0; p < KW; ++p) { rAB[p] = (f32x2){0.f,0.f}; rPQ[p] = (f32x2){0.f,0.f}; }

    const int ty = t >> 4, tx = t & 15;
    const bool valid = (h0 + ty < HOUT) && (w0 + tx < WOUT);
    float partial = 0.f;

    // Phase A worker: one 2-output W-conv task; u in [0,416).
    auto phaseA = [&](int u) {
        const int sl = (u >= 208) ? 1 : 0;
        const int v = u - sl * 208;
        const int r = v >> 3, c0 = (v & 7) * 2;
        const float* r0 = &rawf[sl * SLICE_F + r * ROWF + c0];
        // packed (img1, img2) pairs; two b32 reads 112B apart -> ds_read2_b32
        f32x2 xp[12];
        #pragma unroll
        for (int m = 0; m < 12; ++m) {
            f32x2 v2; v2.x = r0[m]; v2.y = r0[m + 28];
            xp[m] = v2;
        }
        f32x2 s12[2] = {{0.f,0.f},{0.f,0.f}};
        #pragma unroll
        for (int k = 0; k < KW; ++k) {
            s12[0] = pk_fma_s(w2[k], xp[k],     s12[0]);
            s12[1] = pk_fma_s(w2[k], xp[k + 1], s12[1]);
        }
        #pragma unroll
        for (int m = 0; m < 12; ++m) {     // in-place: xp <- (x*y, x^2+y^2)
            const float x = xp[m].x, y = xp[m].y;
            f32x2 p; p.x = x * y; p.y = fmaf(x, x, y * y);
            xp[m] = p;
        }
        f32x2 s34[2] = {{0.f,0.f},{0.f,0.f}};
        #pragma unroll
        for (int k = 0; k < KW; ++k) {
            s34[0] = pk_fma_s(w2[k], xp[k],     s34[0]);
            s34[1] = pk_fma_s(w2[k], xp[k + 1], s34[1]);
        }
        #pragma unroll
        for (int o = 0; o < 2; ++o) {
            float* dst = (float*)&A4[sl][r][c0 + o];
            *(f32x2*)(dst)     = s12[o];
            *(f32x2*)(dst + 2) = s34[o];
        }
    };

    // ---- prologue: stage slices d0, d0+1 directly to LDS ----
    gl_lds16(tp[0], tl[0]); gl_lds16(tp[1], tl[1]); gl_lds16(tp[2], tl[2]);
    tp[0] += tstr[0]; tp[1] += tstr[1]; tp[2] += tstr[2];
    __syncthreads();   // drains vmcnt -> raw ready

    int jj = 0;        // (2i) % 11
    for (int i = 0; i < NIT; ++i) {
        // ---- phase A: both slices' W-convs (416 tasks over 256 threads) ----
        phaseA(t);
        if (t < 160) phaseA(t + 256);
        __syncthreads();   // A4 ready; raw fully consumed

        // ---- issue staging for next slice pair (lands before next barrier) ----
        if (i + 1 < NIT) {
            gl_lds16(tp[0], tl[0]); gl_lds16(tp[1], tl[1]); gl_lds16(tp[2], tl[2]);
            tp[0] += tstr[0]; tp[1] += tstr[1]; tp[2] += tstr[2];
        }

        // ---- phase B: packed H-conv both slices, ring x2, emit x2 ----
        f32x2 fa12={0.f,0.f}, fa34={0.f,0.f}, fb12={0.f,0.f}, fb34={0.f,0.f};
        #pragma unroll
        for (int kh = 0; kh < KW; ++kh) {
            const f32x2* pa = (const f32x2*)&A4[0][ty + kh][tx];
            const f32x2* pb = (const f32x2*)&A4[1][ty + kh][tx];
            fa12 = pk_fma_s(w2[kh], pa[0], fa12);
            fa34 = pk_fma_s(w2[kh], pa[1], fa34);
            fb12 = pk_fma_s(w2[kh], pb[0], fb12);
            fb34 = pk_fma_s(w2[kh], pb[1], fb34);
        }

        const bool emit = (i >= 5);
        f32x2 oa12={0.f,0.f}, oa34={0.f,0.f}, ob12={0.f,0.f}, ob34={0.f,0.f};
        switch (jj) {
            #define CASE2(J) case J: \
                acc_step<J>(rAB, rPQ, w2, fa12, fa34, emit, oa12, oa34); \
                acc_step<(J+1)%KW>(rAB, rPQ, w2, fb12, fb34, emit, ob12, ob34); \
                break;
            CASE2(0) CASE2(1) CASE2(2) CASE2(3) CASE2(4) CASE2(5)
            CASE2(6) CASE2(7) CASE2(8) CASE2(9) CASE2(10)
            #undef CASE2
        }
        jj += 2; if (jj >= KW) jj -= KW;

        if (emit && valid) {
            {
                const float mu1 = oa12.x, mu2 = oa12.y;
                const float m11 = mu1 * mu1, m22 = mu2 * mu2, m12 = mu1 * mu2;
                const float num = (2.f * m12 + SSIM_C1) * (2.f * (oa34.x - m12) + SSIM_C2);
                const float den = (m11 + m22 + SSIM_C1) * ((oa34.y - m11 - m22) + SSIM_C2);
                partial += num * __builtin_amdgcn_rcpf(den);
            }
            {
                const float mu1 = ob12.x, mu2 = ob12.y;
                const float m11 = mu1 * mu1, m22 = mu2 * mu2, m12 = mu1 * mu2;
                const float num = (2.f * m12 + SSIM_C1) * (2.f * (ob34.x - m12) + SSIM_C2);
                const float den = (m11 + m22 + SSIM_C1) * ((ob34.y - m11 - m22) + SSIM_C2);
                partial += num * __builtin_amdgcn_rcpf(den);
            }
        }
        __syncthreads();   // new raw staged + A4 consumed -> next iteration
    }

    // ---- block reduction -> per-block partial sum ----
    #pragma unroll
    for (int off = 32; off >= 1; off >>= 1)
        partial += __shfl_down(partial, off, 64);
    if ((t & 63) == 0) red[t >> 6] = partial;
    __syncthreads();
    if (t == 0) {
        bsum[(blockIdx.z * gridDim.y + blockIdx.y) * gridDim.x + blockIdx.x]
            = red[0] + red[1] + red[2] + red[3];
    }
}

static __global__ __launch_bounds__(256) void ssim_reduce(
    const float* __restrict__ bsum, float* __restrict__ out)
{
    __shared__ double red[4];
    const int t = threadIdx.x;
    double s = 0.0;
    for (int i = t; i < NBLK; i += 256) s += (double)bsum[i];
    #pragma unroll
    for (int off = 32; off >= 1; off >>= 1)
        s += __shfl_down(s, off, 64);
    if ((t & 63) == 0) red[t >> 6] = s;
    __syncthreads();
    if (t == 0) {
        const double tot = red[0] + red[1] + red[2] + red[3];
        out[0] = (float)(tot / (double)((long)NB * DOUT * HOUT * WOUT));
    }
}

extern "C" void kernel_launch(void* const* d_in, const int* in_sizes, int n_in,
                              void* d_out, int out_size, void* d_ws, size_t ws_size,
                              hipStream_t stream)
{
    const float* img1 = (const float*)d_in[0];
    const float* img2 = (const float*)d_in[1];
    const float* win  = (const float*)d_in[2];
    float* out  = (float*)d_out;
    float* bsum = (float*)d_ws;   // 2048 floats = 8 KB scratch

    dim3 grid(TW, TH, NB * DCH);
    ssim_main<<<grid, 256, 0, stream>>>(img1, img2, win, bsum);
    ssim_reduce<<<1, 256, 0, stream>>>(bsum, out);
}